// Round 6
// baseline (547.498 us; speedup 1.0000x reference)
//
#include <hip/hip_runtime.h>

#define S_LEN 2048
#define NL 51
#define LS 53
#define ST 51
#define EN 52
#define NBATCH 256
#define L2E 1.4426950408889634f
#define LN2 0.6931471805599453f

typedef float f32x4 __attribute__((ext_vector_type(4)));
typedef unsigned int u32x2 __attribute__((ext_vector_type(2)));

__device__ __forceinline__ float rlane(float v, int l) {
    return __builtin_bit_cast(float, __builtin_amdgcn_readlane(__builtin_bit_cast(int, v), l));
}

// v_mov_b32 with DPP lane permute (pure VALU, VGPR->VGPR)
#define DPP(SRC, CTRL) __builtin_amdgcn_update_dpp(0, (SRC), (CTRL), 0xF, 0xF, false)
// quad_perm[1,0,3,2]=177 (l^1), [2,3,0,1]=78 (l^2), [3,2,1,0]=27 (l^3),
// ROW_MIRROR=0x140 (l^15 within row16), ROW_HALF_MIRROR=0x141 (l^7)

// R12 = R11 chain-split (fwd alpha-scan wave + bwd beta-scan wave + gold wave,
// combine at the midpoint) with the readlane gather replaced by R8's
// hardware-verified XOR all-gather:
//   63 ops: 1 permlane32_swap + 2 permlane16_swap + 60 DPP movs give
//   r(B,X)[l] = e[((l^X)&15) + 16B] for B in 0..3, X in 0..15.
// Coefficients are PER-LANE PERMUTED to match: p(B,X)[l] = er(row l, col c),
// c = ((l^X)&15)+16B. Codegen hardening vs R8's collapse (VGPR=64 < live set):
// p held as 16 named f32x4 (quad-allocated) + asm residency pins after init.
// Scan math identical to R11 (passed, absmax 0): multiplicative domain,
// lagged divisor; fwd divisor = row START sum; bwd divisor = lane-53
// all-ones row; bwd coefficients column-major with ST/EN -100 shift.
__global__ __launch_bounds__(192, 1) void crf_kernel(
    const float* __restrict__ logits,   // [256, 2048, 51]
    const int*   __restrict__ labels,   // [256, 2048]
    const int*   __restrict__ lens,     // [256]
    const float* __restrict__ Tr,       // [53, 53]  (to, from)
    float*       __restrict__ out)      // [256]
{
    const int b   = blockIdx.x;
    const int tid = threadIdx.x;
    const int len = lens[b];
    const int bsteps = len >> 1;          // floor(len/2)
    const int fsteps = len - bsteps;      // ceil(len/2) >= 1

    __shared__ float sh_gold;
    __shared__ float sh_eb[64];
    __shared__ float sh_off2b;

    const float* lg = logits + (long)b * S_LEN * NL;

    float eF = 0.f, off2F = 0.f;          // forward results (read after barrier)

    // ---- 16 p-vec iteration macro ----
#define PALL(M) M(0,0) M(0,1) M(0,2) M(0,3) M(1,0) M(1,1) M(1,2) M(1,3) \
                M(2,0) M(2,1) M(2,2) M(2,3) M(3,0) M(3,1) M(3,2) M(3,3)
#define DECLP(B,G) f32x4 p##B##_##G;
#define LDP(B,G,GETTER) { \
        p##B##_##G.x = GETTER((((lane ^ (4*(G)+0)) & 15) + 16*(B))); \
        p##B##_##G.y = GETTER((((lane ^ (4*(G)+1)) & 15) + 16*(B))); \
        p##B##_##G.z = GETTER((((lane ^ (4*(G)+2)) & 15) + 16*(B))); \
        p##B##_##G.w = GETTER((((lane ^ (4*(G)+3)) & 15) + 16*(B))); }
#define MAXP(B,G) tmax = fmaxf(tmax, \
        fmaxf(fmaxf(p##B##_##G.x, p##B##_##G.y), fmaxf(p##B##_##G.z, p##B##_##G.w)));
#define EXPP(B,G) { \
        p##B##_##G.x = __builtin_amdgcn_exp2f((p##B##_##G.x - tmax) * L2E); \
        p##B##_##G.y = __builtin_amdgcn_exp2f((p##B##_##G.y - tmax) * L2E); \
        p##B##_##G.z = __builtin_amdgcn_exp2f((p##B##_##G.z - tmax) * L2E); \
        p##B##_##G.w = __builtin_amdgcn_exp2f((p##B##_##G.w - tmax) * L2E); }
#define PINP(B,G) asm volatile("" : "+v"(p##B##_##G));

    // ---- 63-op XOR all-gather: r{B}_{X}[l] = e[((l^X)&15) + 16*B] (R8-proven) ----
#define BQ(B) \
        const int r##B##_1 = DPP(r##B##_0, 177); \
        const int r##B##_2 = DPP(r##B##_0, 78);  \
        const int r##B##_3 = DPP(r##B##_0, 27);
#define BH(B) \
        const int r##B##_7 = DPP(r##B##_0, 0x141); \
        const int r##B##_6 = DPP(r##B##_1, 0x141); \
        const int r##B##_5 = DPP(r##B##_2, 0x141); \
        const int r##B##_4 = DPP(r##B##_3, 0x141);
#define BMIR(B) \
        const int r##B##_15 = DPP(r##B##_0, 0x140); \
        const int r##B##_14 = DPP(r##B##_1, 0x140); \
        const int r##B##_13 = DPP(r##B##_2, 0x140); \
        const int r##B##_12 = DPP(r##B##_3, 0x140); \
        const int r##B##_11 = DPP(r##B##_4, 0x140); \
        const int r##B##_10 = DPP(r##B##_5, 0x140); \
        const int r##B##_9  = DPP(r##B##_6, 0x140); \
        const int r##B##_8  = DPP(r##B##_7, 0x140);
#define BCAST \
        const int e_i = __builtin_bit_cast(int, e); \
        const u32x2 sw32 = __builtin_amdgcn_permlane32_swap((unsigned)e_i, (unsigned)e_i, false, false); \
        const u32x2 swA  = __builtin_amdgcn_permlane16_swap(sw32[0], sw32[0], false, false); \
        const u32x2 swB  = __builtin_amdgcn_permlane16_swap(sw32[1], sw32[1], false, false); \
        const int r0_0 = (int)swA[0]; const int r1_0 = (int)swA[1]; \
        const int r2_0 = (int)swB[0]; const int r3_0 = (int)swB[1]; \
        BQ(0) BQ(1) BQ(2) BQ(3) \
        BH(0) BH(1) BH(2) BH(3) \
        BMIR(0) BMIR(1) BMIR(2) BMIR(3)

#define RF(B,X) __builtin_bit_cast(float, r##B##_##X)
#define FB8L(B) { \
        aL##B = fmaf(RF(B,0),  p##B##_0.x, aL##B); aH##B = fmaf(RF(B,1),  p##B##_0.y, aH##B); \
        aL##B = fmaf(RF(B,2),  p##B##_0.z, aL##B); aH##B = fmaf(RF(B,3),  p##B##_0.w, aH##B); \
        aL##B = fmaf(RF(B,4),  p##B##_1.x, aL##B); aH##B = fmaf(RF(B,5),  p##B##_1.y, aH##B); \
        aL##B = fmaf(RF(B,6),  p##B##_1.z, aL##B); aH##B = fmaf(RF(B,7),  p##B##_1.w, aH##B); }
#define FB8H(B) { \
        aL##B = fmaf(RF(B,8),  p##B##_2.x, aL##B); aH##B = fmaf(RF(B,9),  p##B##_2.y, aH##B); \
        aL##B = fmaf(RF(B,10), p##B##_2.z, aL##B); aH##B = fmaf(RF(B,11), p##B##_2.w, aH##B); \
        aL##B = fmaf(RF(B,12), p##B##_3.x, aL##B); aH##B = fmaf(RF(B,13), p##B##_3.y, aH##B); \
        aL##B = fmaf(RF(B,14), p##B##_3.z, aL##B); aH##B = fmaf(RF(B,15), p##B##_3.w, aH##B); }
#define MATVEC(SOUT) { \
        float aL0=0.f,aH0=0.f,aL1=0.f,aH1=0.f,aL2=0.f,aH2=0.f,aL3=0.f,aH3=0.f; \
        FB8L(0) FB8H(0) FB8L(1) FB8H(1) FB8L(2) FB8H(2) FB8L(3) FB8H(3) \
        SOUT = ((aL0+aH0)+(aL1+aH1)) + ((aL2+aH2)+(aL3+aH3)); }

    // DL = divisor lane; MV = mask value for inactive-logit lanes
#define STEP(NLV, DL, MV) { \
        BCAST \
        float sv; MATVEC(sv) \
        e = sv * q; \
        const float ssum = rlane(sv, DL); \
        off2 += lprev; \
        lprev = __builtin_amdgcn_logf(ssum); \
        const float nl = (lane < NL) ? (NLV) : (MV); \
        q = __builtin_amdgcn_exp2f((nl + tmax) * L2E) * __builtin_amdgcn_rcpf(ssum); }

    if (tid >= 128) {
        // ---- wave2: gold score ----
        const int lid = tid - 128;
        const int* lb = labels + (long)b * S_LEN;
        float p = 0.f;
        for (int t = lid; t < len; t += 64) {
            const int lab  = lb[t];
            const int prev = (t == 0) ? ST : lb[t - 1];
            p += lg[(long)t * NL + lab] + Tr[lab * LS + prev];
        }
        if (lid == 0) p += Tr[EN * LS + lb[len - 1]];   // final transition to END
#pragma unroll
        for (int off = 32; off > 0; off >>= 1)
            p += __shfl_down(p, off, 64);
        if (lid == 0) sh_gold = p;
    } else if (tid >= 64) {
        // ---- wave1: backward beta-scan (column-major T', XOR-permuted) ----
        const int lane = tid - 64;
        const int jj = (lane < NL) ? lane : 0;

        PALL(DECLP)
#define GTB(C) (((lane < LS) && ((C) < LS)) ? \
                (Tr[(C) * LS + lane] - ((((C)==ST)||((C)==EN)) ? 100.f : 0.f)) : -1e30f)
#define LDPB(B,G) LDP(B,G,GTB)
        PALL(LDPB)
#undef LDPB
        float tmax = -1e30f;
        PALL(MAXP)
        // p = exp(T' - tmax). Lane 53: all -1e30 -> p == 1 (all-ones row) ->
        // s'[53] = sum of the gather input = the rescale divisor. Lanes with
        // c >= 53 get p = 0 (or lane >= 53: q stays 0, e stays 0).
        PALL(EXPP)
        PALL(PINP)
#undef GTB

        // init: b_len[k] = T[EN,k]; mult domain with global shift 100.
        float rawEN = (lane < LS) ? (Tr[EN * LS + lane] - 100.f) : -1e30f;
        float e     = __builtin_amdgcn_exp2f(rawEN * L2E);
        float off2  = 100.f * L2E;
        float lprev = 0.f;
        float q     = __builtin_amdgcn_exp2f(tmax * L2E);

        float buf[4] = {0.f, 0.f, 0.f, 0.f};
        if (bsteps >= 1) {
            // fold g_{len-1} (source-side logit, mask value 0) into e
            float nlL = (lane < NL) ? lg[(long)(len - 1) * NL + jj] : 0.f;
            e *= __builtin_amdgcn_exp2f(nlL * L2E);
            int r;
            buf[0] = lg[(long)(len - 2) * NL + jj];            // bsteps>=1 -> len>=2
            r = len - 3; r = r < 0 ? 0 : r; buf[1] = lg[(long)r * NL + jj];
            r = len - 4; r = r < 0 ? 0 : r; buf[2] = lg[(long)r * NL + jj];
            r = len - 5; r = r < 0 ? 0 : r; buf[3] = lg[(long)r * NL + jj];
        }

        int i = 0;
#pragma unroll 1
        while (i + 4 <= bsteps) {
            { int pr = len - 6 - i; pr = pr < 0 ? 0 : pr;
              float pf = lg[(long)pr * NL + jj]; STEP(buf[0], 53, 0.f) buf[0] = pf; }
            { int pr = len - 7 - i; pr = pr < 0 ? 0 : pr;
              float pf = lg[(long)pr * NL + jj]; STEP(buf[1], 53, 0.f) buf[1] = pf; }
            { int pr = len - 8 - i; pr = pr < 0 ? 0 : pr;
              float pf = lg[(long)pr * NL + jj]; STEP(buf[2], 53, 0.f) buf[2] = pf; }
            { int pr = len - 9 - i; pr = pr < 0 ? 0 : pr;
              float pf = lg[(long)pr * NL + jj]; STEP(buf[3], 53, 0.f) buf[3] = pf; }
            i += 4;
        }
#pragma unroll
        for (int m = 0; m < 4; ++m) {
            if (i + m < bsteps) { STEP(buf[m], 53, 0.f) }
        }

        sh_eb[lane] = e;
        if (lane == 0) sh_off2b = off2;
    } else {
        // ---- wave0: forward alpha-scan (row-major T, XOR-permuted) ----
        const int lane = tid;
        const int jj = (lane < NL) ? lane : 0;
        const float* trow = Tr + lane * LS;

        PALL(DECLP)
#define GTF(C) (((lane < LS) && ((C) < LS)) ? trow[(C)] : -1e30f)
#define LDPF(B,G) LDP(B,G,GTF)
        PALL(LDPF)
#undef LDPF
        float tmax = -1e30f;
        PALL(MAXP)
        PALL(EXPP)
        PALL(PINP)
#undef GTF

        float buf[4];
        buf[0] = lg[0 * NL + jj];
        buf[1] = lg[1 * NL + jj];
        buf[2] = lg[2 * NL + jj];
        buf[3] = lg[3 * NL + jj];          // rows 0..3 in-bounds (len>=1)

        float e     = (lane == ST) ? 1.f : 0.f;   // exp(alpha0)
        float off2  = 0.f;
        float lprev = 0.f;
        float nl0   = (lane < NL) ? buf[0] : -100.f;
        float q     = __builtin_amdgcn_exp2f((nl0 + tmax) * L2E);   // gexp_0

        int t = 0;
#pragma unroll 1
        while (t + 4 <= fsteps) {
            {   // i = 0  (t+4 <= fsteps <= 2047: in-bounds, no clamp)
                float pf = lg[(long)(t + 4) * NL + jj];
                STEP(buf[1], ST, -100.f)
                buf[0] = pf;
            }
            {   // i = 1
                int ti = t + 5; ti = (ti < S_LEN) ? ti : (S_LEN - 1);
                float pf = lg[(long)ti * NL + jj];
                STEP(buf[2], ST, -100.f)
                buf[1] = pf;
            }
            {   // i = 2
                int ti = t + 6; ti = (ti < S_LEN) ? ti : (S_LEN - 1);
                float pf = lg[(long)ti * NL + jj];
                STEP(buf[3], ST, -100.f)
                buf[2] = pf;
            }
            {   // i = 3
                int ti = t + 7; ti = (ti < S_LEN) ? ti : (S_LEN - 1);
                float pf = lg[(long)ti * NL + jj];
                STEP(buf[0], ST, -100.f)
                buf[3] = pf;
            }
            t += 4;
        }
        // tail: slot m holds row t+m; consumed row t+i+1 = slot (i+1)&3
#pragma unroll
        for (int i = 0; i < 4; ++i) {
            if (t + i < fsteps) {
                STEP(buf[(i + 1) & 3], ST, -100.f)
            }
        }

        eF    = e;
        off2F = off2;
    }

    __syncthreads();

    if (tid < 64) {
        // combine: norm = LN2*(off2_f + off2_b + log2(dot(e_fwd, e_bwd)))
        float d = eF * sh_eb[tid];
#pragma unroll
        for (int off = 32; off > 0; off >>= 1)
            d += __shfl_xor(d, off, 64);
        if (tid == 0) {
            float norm = LN2 * (off2F + sh_off2b + __builtin_amdgcn_logf(d));
            out[b] = sh_gold - norm;
        }
    }
}

extern "C" void kernel_launch(void* const* d_in, const int* in_sizes, int n_in,
                              void* d_out, int out_size, void* d_ws, size_t ws_size,
                              hipStream_t stream) {
    const float* logits = (const float*)d_in[0];
    const int*   labels = (const int*)d_in[1];
    const int*   lens   = (const int*)d_in[2];
    const float* Tr     = (const float*)d_in[3];
    float*       out    = (float*)d_out;
    crf_kernel<<<NBATCH, 192, 0, stream>>>(logits, labels, lens, Tr, out);
}